// Round 7
// baseline (252.771 us; speedup 1.0000x reference)
//
#include <hip/hip_runtime.h>
#include <float.h>
#include <math.h>

typedef __attribute__((ext_vector_type(8))) short short8;
typedef __attribute__((ext_vector_type(8))) _Float16 half8;
typedef __attribute__((ext_vector_type(4))) float f32x4;

constexpr int B_N  = 8192;
constexpr int D_KK = 128;
constexpr int NCLS = 50;
constexpr int NCHUNK = 32;             // 256 cols per chunk; chunk = bid&31 -> XCD-affine
constexpr int CCOLS = B_N / NCHUNK;    // 256
constexpr int NPBLK = 32;              // classsum partial blocks
constexpr float C_SCALE = 28.853900817779268f;   // 20*log2(e), folded into A at conversion
constexpr float MARGIN  = 40.0f;                 // skip margin, base-2 units
constexpr float NEG_LOW  = -1.0e5f;
constexpr float NEG_MASK = -1.0e30f;

__device__ __forceinline__ float exp2fast(float x) { return __builtin_amdgcn_exp2f(x); }

// ---------------- prep: A -> f16 row-major (pre-scaled); B -> f16 k-major transpose ----------------
// bT layout: [kq 0..15][col 0..8191][e 0..7]  (kq = k/8)
__global__ void prep_kernel(const float* __restrict__ a, const float* __restrict__ b,
                            short* __restrict__ aH, short* __restrict__ bT)
{
    const int NPER = B_N * D_KK / 8;                  // 131072
    int i = blockIdx.x * blockDim.x + threadIdx.x;    // 0..262143
    if (i < NPER) {
        const f32x4* sp = (const f32x4*)(a + (size_t)i * 8);
        f32x4 v0 = sp[0], v1 = sp[1];
        short8 h;
#pragma unroll
        for (int e = 0; e < 4; ++e) {
            h[e]     = __builtin_bit_cast(short, (_Float16)(C_SCALE * v0[e]));
            h[e + 4] = __builtin_bit_cast(short, (_Float16)(C_SCALE * v1[e]));
        }
        *(short8*)(aH + (size_t)i * 8) = h;
    } else {
        int j   = i - NPER;          // 0..131071
        int kq  = j & 15;            // k-group
        int col = j >> 4;            // 0..8191
        const f32x4* sp = (const f32x4*)(b + (size_t)col * D_KK + kq * 8);
        f32x4 v0 = sp[0], v1 = sp[1];
        short8 h;
#pragma unroll
        for (int e = 0; e < 4; ++e) {
            h[e]     = __builtin_bit_cast(short, (_Float16)v0[e]);
            h[e + 4] = __builtin_bit_cast(short, (_Float16)v1[e]);
        }
        *(short8*)(bT + (size_t)kq * B_N * 8 + (size_t)col * 8) = h;
    }
}

// ---------------- main: no LDS, no barriers. Wave = 32 rows x 256 cols sweep ----------------
// Grid 2048 = 8 blocks/CU, 32 waves/CU (full occupancy); VGPR capped at 64 by launch_bounds.
__global__ __launch_bounds__(256, 8)
void rowstats_kernel(const short* __restrict__ aH, const short* __restrict__ bT,
                     const int* __restrict__ labels,
                     float* __restrict__ pmx, float* __restrict__ ps)
{
    const int bid   = blockIdx.x;
    const int chunk = bid & (NCHUNK - 1);
    const int R0    = (bid >> 5) * 128;
    const int C0    = chunk * CCOLS;

    const int tid = threadIdx.x;
    const int wid = tid >> 6, l = tid & 63;
    const int l15 = l & 15, l16 = l >> 4;
    const int wrow = R0 + wid * 32;

    // ---- A fragments -> registers: wave's 32 rows x 128 K ----
    half8 aF[2][4];                                         // [mf][ks]
#pragma unroll
    for (int mf = 0; mf < 2; ++mf) {
        const int arow = wrow + mf * 16 + l15;
#pragma unroll
        for (int ks = 0; ks < 4; ++ks)
            aF[mf][ks] = __builtin_bit_cast(half8,
                *(const short8*)(aH + (size_t)arow * D_KK + ks * 32 + l16 * 8));
    }

    int labA[8];
#pragma unroll
    for (int mf = 0; mf < 2; ++mf)
#pragma unroll
        for (int r = 0; r < 4; ++r)
            labA[mf * 4 + r] = labels[wrow + mf * 16 + l16 * 4 + r];

    float mx[8], sm[8];
#pragma unroll
    for (int i = 0; i < 8; ++i) { mx[i] = NEG_LOW; sm[i] = 0.0f; }

    // per-lane B fragment base pointers: [nf][ks], advance 32 cols (=256 shorts) per tile
    const short* bBase[2][4];
#pragma unroll
    for (int nf = 0; nf < 2; ++nf)
#pragma unroll
        for (int ks = 0; ks < 4; ++ks)
            bBase[nf][ks] = bT + (size_t)(ks * 4 + l16) * B_N * 8
                               + (size_t)(C0 + nf * 16 + l15) * 8;

    const int NT = CCOLS / 32;   // 8 tiles of 32 cols

#pragma unroll 2
    for (int t = 0; t < NT; ++t) {
        half8 bF[2][4];
#pragma unroll
        for (int nf = 0; nf < 2; ++nf)
#pragma unroll
            for (int ks = 0; ks < 4; ++ks)
                bF[nf][ks] = __builtin_bit_cast(half8,
                    *(const short8*)(bBase[nf][ks] + t * 256));

        f32x4 acc[2][2];
#pragma unroll
        for (int mf = 0; mf < 2; ++mf)
#pragma unroll
            for (int nf = 0; nf < 2; ++nf) acc[mf][nf] = f32x4{0.f, 0.f, 0.f, 0.f};

#pragma unroll
        for (int ks = 0; ks < 4; ++ks)
#pragma unroll
            for (int mf = 0; mf < 2; ++mf)
#pragma unroll
                for (int nf = 0; nf < 2; ++nf)
                    acc[mf][nf] = __builtin_amdgcn_mfma_f32_16x16x32_f16(
                        aF[mf][ks], bF[nf][ks], acc[mf][nf], 0, 0, 0);

        // ---- epilogue: masked online (max,sum), base-2 units, skip vote per mf ----
        const int colB = C0 + t * 32;
        int lB[2];
#pragma unroll
        for (int nf = 0; nf < 2; ++nf) lB[nf] = labels[colB + nf * 16 + l15];

#pragma unroll
        for (int mf = 0; mf < 2; ++mf) {
            float gm = fmaxf(fmaxf(fmaxf(acc[mf][0][0], acc[mf][0][1]),
                                   fmaxf(acc[mf][0][2], acc[mf][0][3])),
                             fmaxf(fmaxf(acc[mf][1][0], acc[mf][1][1]),
                                   fmaxf(acc[mf][1][2], acc[mf][1][3])));
            int sk = 1;
#pragma unroll
            for (int r = 0; r < 4; ++r) sk &= (gm < mx[mf * 4 + r] - MARGIN) ? 1 : 0;
            if (!__all(sk)) {
#pragma unroll
                for (int r = 0; r < 4; ++r) {
                    const int i = mf * 4 + r;
                    float v0 = (lB[0] != labA[i]) ? acc[mf][0][r] : NEG_MASK;
                    float v1 = (lB[1] != labA[i]) ? acc[mf][1][r] : NEG_MASK;
                    float nm = fmaxf(mx[i], fmaxf(v0, v1));
                    float e  = exp2fast(v0 - nm) + exp2fast(v1 - nm);
                    sm[i] = sm[i] * exp2fast(mx[i] - nm) + e;
                    mx[i] = nm;
                }
            }
        }
    }

    // ---- intra-wave reduce across 16 column-lanes (full column set per row) ----
#pragma unroll
    for (int i = 0; i < 8; ++i) {
#pragma unroll
        for (int off = 1; off < 16; off <<= 1) {
            float m2 = __shfl_xor(mx[i], off);
            float s2 = __shfl_xor(sm[i], off);
            float nm = fmaxf(mx[i], m2);
            sm[i] = sm[i] * exp2fast(mx[i] - nm) + s2 * exp2fast(m2 - nm);
            mx[i] = nm;
        }
    }
    if (l15 == 0) {
#pragma unroll
        for (int mf = 0; mf < 2; ++mf)
#pragma unroll
            for (int r = 0; r < 4; ++r) {
                int row = wrow + mf * 16 + l16 * 4 + r;
                pmx[chunk * B_N + row] = mx[mf * 4 + r];   // base-2 units
                ps [chunk * B_N + row] = sm[mf * 4 + r];
            }
    }
}

// ---------------- per-row chunk combine + per-block class partials (no global atomics) ----------------
__global__ void classsum_kernel(const float* __restrict__ pmx, const float* __restrict__ ps,
                                const int* __restrict__ labels,
                                float* __restrict__ partSum, unsigned int* __restrict__ partCnt)
{
    __shared__ float        csL[NCLS];
    __shared__ unsigned int ccL[NCLS];
    int t = threadIdx.x;
    if (t < NCLS) { csL[t] = 0.0f; ccL[t] = 0u; }
    __syncthreads();

    int j = blockIdx.x * blockDim.x + t;
    float m = -FLT_MAX, s = 0.0f;
#pragma unroll 4
    for (int c = 0; c < NCHUNK; ++c) {
        float m2 = pmx[(size_t)c * B_N + j];
        float s2 = ps [(size_t)c * B_N + j];
        float nm = fmaxf(m, m2);
        s = s * exp2fast(m - nm) + s2 * exp2fast(m2 - nm);
        m = nm;
    }
    int lab = labels[j];
    atomicAdd(&csL[lab], s);
    atomicAdd(&ccL[lab], 1u);
    __syncthreads();
    if (t < NCLS) {
        partSum[blockIdx.x * NCLS + t] = csL[t];
        partCnt[blockIdx.x * NCLS + t] = ccL[t];
    }
}

__global__ void loss_kernel(const float* __restrict__ partSum,
                            const unsigned int* __restrict__ partCnt,
                            float* __restrict__ out)
{
    int c = threadIdx.x;  // 64 threads = 1 wave
    float cs = 0.0f;
    unsigned int cc = 0u;
    if (c < NCLS) {
#pragma unroll 4
        for (int b = 0; b < NPBLK; ++b) {
            cs += partSum[b * NCLS + c];
            cc += partCnt[b * NCLS + c];
        }
    }

    float tot = cs;
#pragma unroll
    for (int off = 1; off < 64; off <<= 1) tot += __shfl_xor(tot, off);

    float contrib = 0.0f;
    if (c < NCLS && cc > 0u) {
        float negc = (float)(B_N - (int)cc);
        float nds  = tot - cs;
        float x    = (negc > 0.0f) ? (nds / negc) : nds;
        float lp   = (cc >= 2u) ? (-logf(x + 1e-12f)) : 0.0f;
        contrib = (float)cc * lp;
    }
#pragma unroll
    for (int off = 1; off < 64; off <<= 1) contrib += __shfl_xor(contrib, off);
    if (c == 0) out[0] = -(contrib / (float)B_N);
}

extern "C" void kernel_launch(void* const* d_in, const int* in_sizes, int n_in,
                              void* d_out, int out_size, void* d_ws, size_t ws_size,
                              hipStream_t stream)
{
    const float* anchor = (const float*)d_in[0];
    const float* target = (const float*)d_in[1];
    const int*   labels = (const int*)d_in[2];
    float* out = (float*)d_out;

    const size_t PLANE = (size_t)B_N * D_KK * sizeof(short);   // 2 MB
    char* ws = (char*)d_ws;
    short* aH = (short*)(ws + 0 * PLANE);
    short* bT = (short*)(ws + 1 * PLANE);
    float* ps  = (float*)(ws + 2 * PLANE);
    float* pmx = (float*)(ws + 2 * PLANE + sizeof(float) * NCHUNK * B_N);
    char*  cls = ws + 2 * PLANE + 2 * sizeof(float) * NCHUNK * B_N;
    float*        partSum = (float*)cls;
    unsigned int* partCnt = (unsigned int*)(cls + NPBLK * NCLS * sizeof(float));

    prep_kernel<<<2 * (B_N * D_KK / 8) / 256, 256, 0, stream>>>(anchor, target, aH, bT);
    rowstats_kernel<<<(B_N / 128) * NCHUNK, 256, 0, stream>>>(aH, bT, labels, pmx, ps);
    classsum_kernel<<<B_N / 256, 256, 0, stream>>>(pmx, ps, labels, partSum, partCnt);
    loss_kernel<<<1, 64, 0, stream>>>(partSum, partCnt, out);
}

// Round 8
// 53.904 us; speedup vs baseline: 4.6893x; 4.6893x over previous
//
#include <hip/hip_runtime.h>
#include <float.h>
#include <math.h>

typedef __attribute__((ext_vector_type(8))) short short8;
typedef __attribute__((ext_vector_type(8))) _Float16 half8;
typedef __attribute__((ext_vector_type(4))) float f32x4;

constexpr int B_N  = 8192;
constexpr int D_KK = 128;
constexpr int NCLS = 50;
constexpr int NCHUNK = 16;             // 512 cols per chunk; XCD = chunk&7
constexpr int CCOLS = B_N / NCHUNK;    // 512
constexpr int BLK_ROWS = 256;          // 8 waves x 32 rows
constexpr int NPBLK = 32;              // classsum partial blocks
constexpr float C_SCALE = 28.853900817779268f;   // 20*log2(e), folded into A at conversion
constexpr float MARGIN  = 40.0f;                 // skip margin, base-2 units
constexpr float NEG_LOW  = -1.0e5f;
constexpr float NEG_MASK = -1.0e30f;

__device__ __forceinline__ float exp2fast(float x) { return __builtin_amdgcn_exp2f(x); }

__device__ __forceinline__ void async_copy16(void* lds, const void* g) {
    __builtin_amdgcn_global_load_lds((const __attribute__((address_space(1))) unsigned int*)g,
                                     (__attribute__((address_space(3))) unsigned int*)lds,
                                     16, 0, 0);
}

// ---------------- prep: f32 -> f16 row-major; A pre-scaled by C_SCALE ----------------
__global__ void prep_kernel(const float* __restrict__ a, const float* __restrict__ b,
                            short* __restrict__ aH, short* __restrict__ bH)
{
    const int NPER = B_N * D_KK / 8;                  // 131072
    int i = blockIdx.x * blockDim.x + threadIdx.x;    // 0..262143
    const float* src = (i < NPER) ? a : b;
    short*       dst = (i < NPER) ? aH : bH;
    const float  sc  = (i < NPER) ? C_SCALE : 1.0f;
    int j = (i < NPER) ? i : i - NPER;
    const f32x4* sp = (const f32x4*)(src + (size_t)j * 8);
    f32x4 v0 = sp[0], v1 = sp[1];
    short8 h;
#pragma unroll
    for (int e = 0; e < 4; ++e) {
        h[e]     = __builtin_bit_cast(short, (_Float16)(sc * v0[e]));
        h[e + 4] = __builtin_bit_cast(short, (_Float16)(sc * v1[e]));
    }
    *(short8*)(dst + (size_t)j * 8) = h;
}

// ---------------- main: LDS-shared B with 4-deep async ring, counted vmcnt ----------------
// 512 thr = 8 waves, wave w owns rows [R0+32w, R0+32w+32) x all 512 chunk cols.
// B tile (32 cols x 128k f16 = 8 KB) staged once per block via ONE global_load_lds
// per thread (pre-swizzled global source, linear LDS dest), ring of 4 tiles.
__global__ __launch_bounds__(512, 4)
void rowstats_kernel(const short* __restrict__ aH, const short* __restrict__ bH,
                     const int* __restrict__ labels,
                     float* __restrict__ pmx, float* __restrict__ ps)
{
    __shared__ __align__(16) char ring[4][8192];   // 32 KB

    const int bid   = blockIdx.x;
    const int chunk = bid & (NCHUNK - 1);          // XCD-affine (16 rowblk stride == 0 mod 8)
    const int R0    = (bid >> 4) * BLK_ROWS;
    const int C0    = chunk * CCOLS;

    const int tid = threadIdx.x;
    const int wid = tid >> 6, l = tid & 63;
    const int l15 = l & 15, l16 = l >> 4;
    const int wrow = R0 + wid * 32;

    // ---- A fragments -> registers: wave's 32 rows x 128 K ----
    half8 aF[2][4];                                 // [mf][ks]
#pragma unroll
    for (int mf = 0; mf < 2; ++mf) {
        const int arow = wrow + mf * 16 + l15;
#pragma unroll
        for (int ks = 0; ks < 4; ++ks)
            aF[mf][ks] = __builtin_bit_cast(half8,
                *(const short8*)(aH + (size_t)arow * D_KK + ks * 32 + l16 * 8));
    }

    int labA[8];
#pragma unroll
    for (int mf = 0; mf < 2; ++mf)
#pragma unroll
        for (int r = 0; r < 4; ++r)
            labA[mf * 4 + r] = labels[wrow + mf * 16 + l16 * 4 + r];

    float mx[8], sm[8];
#pragma unroll
    for (int i = 0; i < 8; ++i) { mx[i] = NEG_LOW; sm[i] = 0.0f; }

    // staging source: thread tid covers tile bytes [tid*16, tid*16+16):
    // col = tid>>4, linear slot s = tid&15 holds global k-group g = s ^ (col&7)
    const int scol  = tid >> 4;                     // 0..31
    const int sg    = (tid & 15) ^ (scol & 7);
    const short* sbase = bH + (size_t)(C0 + scol) * D_KK + sg * 8;
    char* ldsW = &ring[0][0] + wid * 1024;          // wave-uniform dest base (+lane*16 by HW)

    const int NT = CCOLS / 32;                      // 16 tiles

#define STAGE(t)  async_copy16(ldsW + (((t) & 3) * 8192), sbase + (size_t)((t) & 15) * 32 * D_KK)

    STAGE(0); STAGE(1); STAGE(2);                   // 3 outstanding

    for (int t = 0; t < NT; ++t) {
        asm volatile("s_waitcnt vmcnt(2)" ::: "memory");   // tile t landed; t+1,t+2 in flight
        __builtin_amdgcn_s_barrier();                      // all waves' tile-t DMA landed
        __builtin_amdgcn_sched_barrier(0);
        STAGE(t + 3);                               // overwrites slot consumed at t-1 (safe)

        const char* rb = &ring[t & 3][0];
        f32x4 acc[2][2];
#pragma unroll
        for (int mf = 0; mf < 2; ++mf)
#pragma unroll
            for (int nf = 0; nf < 2; ++nf) acc[mf][nf] = f32x4{0.f, 0.f, 0.f, 0.f};

#pragma unroll
        for (int ks = 0; ks < 4; ++ks) {
            half8 bF[2];
#pragma unroll
            for (int nf = 0; nf < 2; ++nf) {
                int col  = nf * 16 + l15;
                int slot = (ks * 4 + l16) ^ (col & 7);
                bF[nf] = __builtin_bit_cast(half8,
                    *(const short8*)(rb + col * 256 + slot * 16));
            }
#pragma unroll
            for (int mf = 0; mf < 2; ++mf)
#pragma unroll
                for (int nf = 0; nf < 2; ++nf)
                    acc[mf][nf] = __builtin_amdgcn_mfma_f32_16x16x32_f16(
                        aF[mf][ks], bF[nf], acc[mf][nf], 0, 0, 0);
        }

        // ---- epilogue: masked online (max,sum), base-2 units, skip vote per mf ----
        const int colB = C0 + t * 32;
        int lB[2];
#pragma unroll
        for (int nf = 0; nf < 2; ++nf) lB[nf] = labels[colB + nf * 16 + l15];

#pragma unroll
        for (int mf = 0; mf < 2; ++mf) {
            float gm = fmaxf(fmaxf(fmaxf(acc[mf][0][0], acc[mf][0][1]),
                                   fmaxf(acc[mf][0][2], acc[mf][0][3])),
                             fmaxf(fmaxf(acc[mf][1][0], acc[mf][1][1]),
                                   fmaxf(acc[mf][1][2], acc[mf][1][3])));
            int sk = 1;
#pragma unroll
            for (int r = 0; r < 4; ++r) sk &= (gm < mx[mf * 4 + r] - MARGIN) ? 1 : 0;
            if (!__all(sk)) {
#pragma unroll
                for (int r = 0; r < 4; ++r) {
                    const int i = mf * 4 + r;
                    float v0 = (lB[0] != labA[i]) ? acc[mf][0][r] : NEG_MASK;
                    float v1 = (lB[1] != labA[i]) ? acc[mf][1][r] : NEG_MASK;
                    float nm = fmaxf(mx[i], fmaxf(v0, v1));
                    float e  = exp2fast(v0 - nm) + exp2fast(v1 - nm);
                    sm[i] = sm[i] * exp2fast(mx[i] - nm) + e;
                    mx[i] = nm;
                }
            }
        }
        // next iteration's s_barrier (after its vmcnt) doubles as the read-done fence
    }
#undef STAGE

    // ---- intra-wave reduce across 16 column-lanes (full column set per row) ----
#pragma unroll
    for (int i = 0; i < 8; ++i) {
#pragma unroll
        for (int off = 1; off < 16; off <<= 1) {
            float m2 = __shfl_xor(mx[i], off);
            float s2 = __shfl_xor(sm[i], off);
            float nm = fmaxf(mx[i], m2);
            sm[i] = sm[i] * exp2fast(mx[i] - nm) + s2 * exp2fast(m2 - nm);
            mx[i] = nm;
        }
    }
    if (l15 == 0) {
#pragma unroll
        for (int mf = 0; mf < 2; ++mf)
#pragma unroll
            for (int r = 0; r < 4; ++r) {
                int row = wrow + mf * 16 + l16 * 4 + r;
                pmx[chunk * B_N + row] = mx[mf * 4 + r];   // base-2 units
                ps [chunk * B_N + row] = sm[mf * 4 + r];
            }
    }
}

// ---------------- per-row chunk combine + per-block class partials (no atomics/memset) ----------------
__global__ void classsum_kernel(const float* __restrict__ pmx, const float* __restrict__ ps,
                                const int* __restrict__ labels,
                                float* __restrict__ partSum, unsigned int* __restrict__ partCnt)
{
    __shared__ float        csL[NCLS];
    __shared__ unsigned int ccL[NCLS];
    int t = threadIdx.x;
    if (t < NCLS) { csL[t] = 0.0f; ccL[t] = 0u; }
    __syncthreads();

    int j = blockIdx.x * blockDim.x + t;
    float m = -FLT_MAX, s = 0.0f;
#pragma unroll 4
    for (int c = 0; c < NCHUNK; ++c) {
        float m2 = pmx[(size_t)c * B_N + j];
        float s2 = ps [(size_t)c * B_N + j];
        float nm = fmaxf(m, m2);
        s = s * exp2fast(m - nm) + s2 * exp2fast(m2 - nm);
        m = nm;
    }
    int lab = labels[j];
    atomicAdd(&csL[lab], s);
    atomicAdd(&ccL[lab], 1u);
    __syncthreads();
    if (t < NCLS) {
        partSum[blockIdx.x * NCLS + t] = csL[t];
        partCnt[blockIdx.x * NCLS + t] = ccL[t];
    }
}

__global__ void loss_kernel(const float* __restrict__ partSum,
                            const unsigned int* __restrict__ partCnt,
                            float* __restrict__ out)
{
    int c = threadIdx.x;  // 64 threads = 1 wave
    float cs = 0.0f;
    unsigned int cc = 0u;
    if (c < NCLS) {
#pragma unroll 4
        for (int b = 0; b < NPBLK; ++b) {
            cs += partSum[b * NCLS + c];
            cc += partCnt[b * NCLS + c];
        }
    }

    float tot = cs;
#pragma unroll
    for (int off = 1; off < 64; off <<= 1) tot += __shfl_xor(tot, off);

    float contrib = 0.0f;
    if (c < NCLS && cc > 0u) {
        float negc = (float)(B_N - (int)cc);
        float nds  = tot - cs;
        float x    = (negc > 0.0f) ? (nds / negc) : nds;
        float lp   = (cc >= 2u) ? (-logf(x + 1e-12f)) : 0.0f;
        contrib = (float)cc * lp;
    }
#pragma unroll
    for (int off = 1; off < 64; off <<= 1) contrib += __shfl_xor(contrib, off);
    if (c == 0) out[0] = -(contrib / (float)B_N);
}

extern "C" void kernel_launch(void* const* d_in, const int* in_sizes, int n_in,
                              void* d_out, int out_size, void* d_ws, size_t ws_size,
                              hipStream_t stream)
{
    const float* anchor = (const float*)d_in[0];
    const float* target = (const float*)d_in[1];
    const int*   labels = (const int*)d_in[2];
    float* out = (float*)d_out;

    const size_t PLANE = (size_t)B_N * D_KK * sizeof(short);   // 2 MB
    char* ws = (char*)d_ws;
    short* aH = (short*)(ws + 0 * PLANE);
    short* bH = (short*)(ws + 1 * PLANE);
    float* ps  = (float*)(ws + 2 * PLANE);
    float* pmx = (float*)(ws + 2 * PLANE + sizeof(float) * NCHUNK * B_N);
    char*  cls = ws + 2 * PLANE + 2 * sizeof(float) * NCHUNK * B_N;
    float*        partSum = (float*)cls;
    unsigned int* partCnt = (unsigned int*)(cls + NPBLK * NCLS * sizeof(float));

    prep_kernel<<<2 * (B_N * D_KK / 8) / 256, 256, 0, stream>>>(anchor, target, aH, bH);
    rowstats_kernel<<<(B_N / BLK_ROWS) * NCHUNK, 512, 0, stream>>>(aH, bH, labels, pmx, ps);
    classsum_kernel<<<B_N / 256, 256, 0, stream>>>(pmx, ps, labels, partSum, partCnt);
    loss_kernel<<<1, 64, 0, stream>>>(partSum, partCnt, out);
}